// Round 24
// baseline (1393.002 us; speedup 1.0000x reference)
//
#include <hip/hip_runtime.h>
#include <hip/hip_bf16.h>
#include <stdint.h>

#define B 8
#define S 1024
#define L 1025
#define D 512
#define H 8
#define HD 64
#define NL 6
#define FF 2048
#define MAXD 64
#define OUTLEN 8
#define NC 10

#define MP 8320   // 65 * 128, padded M

typedef __bf16 bf16;
typedef __bf16 bf16x8 __attribute__((ext_vector_type(8)));
typedef __bf16 bf16x4 __attribute__((ext_vector_type(4)));
typedef __bf16 bf16x2 __attribute__((ext_vector_type(2)));
typedef float f32x4 __attribute__((ext_vector_type(4)));

__device__ __forceinline__ float fexp2(float x) { return __builtin_amdgcn_exp2f(x); }

// barrier WITHOUT the vmcnt(0) drain
#define LGKM_BARRIER() asm volatile("s_waitcnt lgkmcnt(0)\ns_barrier" ::: "memory")

__device__ __forceinline__ void gld16(const void* g, void* l) {
    __builtin_amdgcn_global_load_lds(
        (const __attribute__((address_space(1))) unsigned int*)g,
        (__attribute__((address_space(3))) unsigned int*)l,
        16, 0, 0);
}

// GELU with A&S 7.1.26 erf (|err| <= 1.5e-7), no libm call
__device__ __forceinline__ float fast_gelu(float v) {
    float x = v * 0.70710678118654752f;
    float ax = fabsf(x);
    float t = 1.f / fmaf(0.3275911f, ax, 1.f);
    float poly = t * (0.254829592f + t * (-0.284496736f + t * (1.421413741f +
                 t * (-1.453152027f + t * 1.061405429f))));
    float e = fexp2(-ax * ax * 1.4426950408889634f);
    float erfv = 1.f - poly * e;
    erfv = copysignf(erfv, x);
    return 0.5f * v * (1.f + erfv);
}

// ---------------- f32 -> bf16 conversion (vectorized) ----------------
__global__ __launch_bounds__(256) void cvt_k(const float* __restrict__ in,
                                             bf16* __restrict__ out, int n4)
{
    int i = blockIdx.x * 256 + threadIdx.x;
    if (i >= n4) return;
    float4 v = reinterpret_cast<const float4*>(in)[i];
    bf16x4 o;
    o[0] = (bf16)v.x; o[1] = (bf16)v.y; o[2] = (bf16)v.z; o[3] = (bf16)v.w;
    reinterpret_cast<bf16x4*>(out)[i] = o;
}

// ---------------- embedding (bf16 out only) ----------------
__global__ void embed_k(const int* __restrict__ src, const float* __restrict__ emb,
                        const float* __restrict__ cls, bf16* __restrict__ xb)
{
    long i = (long)blockIdx.x * blockDim.x + threadIdx.x;
    if (i >= (long)B * L * D) return;
    int d = (int)(i % D);
    long bl = i / D;
    int l = (int)(bl % L);
    int b = (int)(bl / L);
    float v = (l == 0) ? cls[d] : emb[(long)src[b * S + (l - 1)] * D + d];
    xb[i] = (bf16)v;
}

// ---------------- MFMA bf16 GEMM, 2-phase double-buffered LDS ----------------
// COMB=1 (RT=64 only): A-panel = s1*A + s2*A2 combined on the fly during
// staging (reg load both partials + ml blend + ds_write to the same linear
// LDS slot gld16 would use). Fuses the flash-decode combine into this GEMM.
template<int ACT, int OBF, int BIAS, int RT, int COMB>
__global__ __launch_bounds__(256) void mgemm(const bf16* __restrict__ A,
                                             const bf16* __restrict__ A2,
                                             const float2* __restrict__ mlp,
                                             const bf16* __restrict__ W,
                                             const float* __restrict__ bias,
                                             float* __restrict__ Cf,
                                             bf16* __restrict__ Cb,
                                             int N, int K, int LDA)
{
    __shared__ bf16 Asl[2][RT * 32];
    __shared__ bf16 Bsl[2][128 * 32];
    int tid = threadIdx.x;
    int m0 = blockIdx.y * RT;
    int n0 = blockIdx.x * 128;
    int lane = tid & 63;
    int w = tid >> 6;
    int wbase = tid & ~63;
    int kb = (lane >> 4) * 8;
    int rsel = lane & 15;
    constexpr int FJ = (RT == 128) ? 4 : 2;
    constexpr int CW = (RT == 128) ? 64 : 32;
    int wr, wc;
    if constexpr (RT == 128) { wr = w >> 1; wc = w & 1; }
    else                     { wr = 0;      wc = w;     }
    f32x4 acc[4][FJ] = {};

    // COMB: per-thread row is fixed (m0 + tid/4); head varies with k0.
    int crow = 0, cb_ = 0, cq = 0;
    bool crow_ok = false;
    if constexpr (COMB) {
        crow = m0 + (tid >> 2);
        crow_ok = (crow < B * L);
        if (crow_ok) {
            cb_ = crow / 1025;
            cq = crow - cb_ * 1025;
        }
    }

    auto stage = [&](int buf, int k0) {
        if constexpr (RT == 128) {
#pragma unroll
            for (int r = 0; r < 2; r++) {
                int s = r * 256 + tid;
                int sb = r * 256 + wbase;
                gld16(A + (size_t)(m0 + (s >> 2)) * LDA + k0 + (s & 3) * 8, &Asl[buf][(size_t)sb * 8]);
                gld16(W + (size_t)(n0 + (s >> 2)) * LDA + k0 + (s & 3) * 8, &Bsl[buf][(size_t)sb * 8]);
            }
        } else {
            if constexpr (COMB) {
                int col = k0 + (tid & 3) * 8;        // chunk within one head
                float s1 = 1.f, s2 = 0.f;
                if (crow_ok) {
                    int h = col >> 6;
                    float2 a = mlp[(size_t)(cb_ * 8 + h) * 1025 + cq];
                    float2 c = mlp[(size_t)(64 + cb_ * 8 + h) * 1025 + cq];
                    float m = fmaxf(a.x, c.x);
                    s1 = a.y * fexp2(a.x - m);
                    s2 = c.y * fexp2(c.x - m);
                    float inv = 1.f / (s1 + s2);
                    s1 *= inv; s2 *= inv;
                }
                bf16x8 v0 = *(const bf16x8*)(A + (size_t)crow * LDA + col);
                bf16x8 v1 = *(const bf16x8*)(A2 + (size_t)crow * LDA + col);
                bf16x8 o;
#pragma unroll
                for (int j = 0; j < 8; j++)
                    o[j] = (bf16)(s1 * (float)v0[j] + s2 * (float)v1[j]);
                *(bf16x8*)&Asl[buf][(size_t)tid * 8] = o;   // same slot gld16 uses
            } else {
                gld16(A + (size_t)(m0 + (tid >> 2)) * LDA + k0 + (tid & 3) * 8, &Asl[buf][(size_t)wbase * 8]);
            }
#pragma unroll
            for (int r = 0; r < 2; r++) {
                int s = r * 256 + tid;
                int sb = r * 256 + wbase;
                gld16(W + (size_t)(n0 + (s >> 2)) * LDA + k0 + (s & 3) * 8, &Bsl[buf][(size_t)sb * 8]);
            }
        }
    };

    stage(0, 0);
    __syncthreads();

    for (int k0 = 0; k0 < K; k0 += 32) {
        int cur = (k0 >> 5) & 1;
        if (k0 + 32 < K) stage(cur ^ 1, k0 + 32);
        bf16x8 af[4], bfr[FJ];
#pragma unroll
        for (int fi = 0; fi < 4; fi++)
            af[fi] = *reinterpret_cast<const bf16x8*>(&Asl[cur][(wr * 64 + fi * 16 + rsel) * 32 + kb]);
#pragma unroll
        for (int fj = 0; fj < FJ; fj++)
            bfr[fj] = *reinterpret_cast<const bf16x8*>(&Bsl[cur][(wc * CW + fj * 16 + rsel) * 32 + kb]);
#pragma unroll
        for (int fi = 0; fi < 4; fi++)
#pragma unroll
            for (int fj = 0; fj < FJ; fj++)
                acc[fi][fj] = __builtin_amdgcn_mfma_f32_16x16x32_bf16(af[fi], bfr[fj], acc[fi][fj], 0, 0, 0);
        __syncthreads();
    }
    int rowb = (lane >> 4) * 4;
    int colb = lane & 15;
#pragma unroll
    for (int fi = 0; fi < 4; fi++) {
#pragma unroll
        for (int fj = 0; fj < FJ; fj++) {
            int col = n0 + wc * CW + fj * 16 + colb;
            float bsv = BIAS ? bias[col] : 0.f;
#pragma unroll
            for (int i = 0; i < 4; i++) {
                int row = m0 + wr * 64 + fi * 16 + rowb + i;
                float v = acc[fi][fj][i] + bsv;
                if (ACT) v = fast_gelu(v);
                if (OBF) Cb[(size_t)row * N + col] = (bf16)v;
                else     Cf[(size_t)row * N + col] = v;
            }
        }
    }
}

// ---------------- MFMA flash attention v10: KV-split + defer-max (T13) -------
__global__ __launch_bounds__(256) void fattn_k(const bf16* __restrict__ qkv,
                                               const float* __restrict__ rel_emb_l,
                                               const unsigned char* __restrict__ pad,
                                               bf16* __restrict__ op0,
                                               bf16* __restrict__ op1,
                                               float2* __restrict__ mlout)
{
    constexpr int PIT = 72;
    __shared__ bf16 Vt[3][64 * PIT];
    __shared__ bf16 Psh[4][2][16 * PIT];
    __shared__ float bias2s[2 * MAXD + 1];
    __shared__ float colm[2][64];

    const int bh = blockIdx.x;
    const int qt = blockIdx.y;
    const int z = blockIdx.z;
    const int tbeg = z ? 9 : 0;
    const int tend = z ? 17 : 9;
    bf16* opart = z ? op1 : op0;
    const int h = bh & 7, b = bh >> 3;
    const int q0 = qt * 128;
    const int tid = threadIdx.x;
    const int lane = tid & 63;
    const int w = tid >> 6;
    const int ln15 = lane & 15, g4 = lane >> 4;
    const int kb8 = g4 * 8;
    constexpr float LOG2E = 1.4426950408889634f;
    constexpr float C2 = 0.125f * LOG2E;

    const char* base = (const char*)qkv + (size_t)(b * L) * 3072 + (size_t)h * (HD * 2);

    for (int i = tid; i < 2 * MAXD + 1; i += 256) bias2s[i] = rel_emb_l[i * H + h] * LOG2E;
    if (tid < 64) {
        int gk0 = tbeg * 64 + tid;
        int pi = (gk0 > 0 && gk0 <= 1024) ? gk0 - 1 : 0;
        colm[tbeg & 1][tid] = (gk0 > 1024 || (gk0 > 0 && pad[(size_t)b * S + pi])) ? -1e9f : 0.f;
    }

    int qrow[2];
    bf16x8 qa[2][2];
#pragma unroll
    for (int qq = 0; qq < 2; qq++) {
        qrow[qq] = q0 + qq * 64 + w * 16 + ln15;
        qa[qq][0] = *(const bf16x8*)(base + (size_t)qrow[qq] * 3072 + g4 * 16);
        qa[qq][1] = *(const bf16x8*)(base + (size_t)qrow[qq] * 3072 + 64 + g4 * 16);
    }

    const int vr = tid >> 3;
    const int vd0 = (tid & 7) * 8;
    const int vsw = ((vd0 >> 3) & 7) << 3;

    { // prologue: stage V tile tbeg into Vt[0]
        int kv0 = tbeg * 64;
        bf16x8 a = *(const bf16x8*)(base + (size_t)(kv0 + vr) * 3072 + 2048 + vd0 * 2);
        bf16x8 c = *(const bf16x8*)(base + (size_t)(kv0 + vr + 32) * 3072 + 2048 + vd0 * 2);
#pragma unroll
        for (int j = 0; j < 8; j++) {
            Vt[0][(vd0 + j) * PIT + (vr ^ vsw)] = a[j];
            Vt[0][(vd0 + j) * PIT + ((vr + 32) ^ vsw)] = c[j];
        }
    }
    bf16x8 kr[4][2];
#pragma unroll
    for (int fj = 0; fj < 4; fj++) {
        const char* rp = base + (size_t)(tbeg * 64 + fj * 16 + ln15) * 3072 + 1024 + g4 * 16;
        kr[fj][0] = *(const bf16x8*)(rp);
        kr[fj][1] = *(const bf16x8*)(rp + 64);
    }
    LGKM_BARRIER();

    f32x4 oacc[2][4] = {};
    float m_prev[2] = {-1e30f, -1e30f};
    float l_sum[2] = {0.f, 0.f};

    int cur3 = 0;
    for (int t = tbeg; t < tend; t++) {
        const int k0 = t * 64;
        const int k0n = (k0 + 64 > 1024) ? 1024 : (k0 + 64);
        const int curM = t & 1;
        int nxt3 = cur3 + 1; if (nxt3 == 3) nxt3 = 0;

        bf16x8 vA = *(const bf16x8*)(base + (size_t)(k0n + vr) * 3072 + 2048 + vd0 * 2);
        bf16x8 vB = *(const bf16x8*)(base + (size_t)(k0n + vr + 32) * 3072 + 2048 + vd0 * 2);

        f32x4 sacc[2][4] = {};
#pragma unroll
        for (int qq = 0; qq < 2; qq++)
#pragma unroll
            for (int fj = 0; fj < 4; fj++) {
                sacc[qq][fj] = __builtin_amdgcn_mfma_f32_16x16x32_bf16(kr[fj][0], qa[qq][0], sacc[qq][fj], 0, 0, 0);
                sacc[qq][fj] = __builtin_amdgcn_mfma_f32_16x16x32_bf16(kr[fj][1], qa[qq][1], sacc[qq][fj], 0, 0, 0);
            }
#pragma unroll
        for (int fj = 0; fj < 4; fj++) {
            const char* rp = base + (size_t)(k0n + fj * 16 + ln15) * 3072 + 1024 + g4 * 16;
            kr[fj][0] = *(const bf16x8*)(rp);
            kr[fj][1] = *(const bf16x8*)(rp + 64);
        }

        f32x4 cm[4];
#pragma unroll
        for (int fj = 0; fj < 4; fj++)
            cm[fj] = *(const f32x4*)&colm[curM][fj * 16 + g4 * 4];

#pragma unroll
        for (int qq = 0; qq < 2; qq++) {
            float sv[4][4];
            const int relbw = k0 - q0 - qq * 64 - w * 16;
            if (relbw >= MAXD + 15 || relbw <= -MAXD - 63) {
                const float bu = bias2s[relbw > 0 ? 2 * MAXD : 0];
#pragma unroll
                for (int fj = 0; fj < 4; fj++)
#pragma unroll
                    for (int i = 0; i < 4; i++)
                        sv[fj][i] = fmaf(sacc[qq][fj][i], C2, bu + cm[fj][i]);
            } else {
                const int relb = k0 - qrow[qq];
#pragma unroll
                for (int fj = 0; fj < 4; fj++)
#pragma unroll
                    for (int i = 0; i < 4; i++) {
                        int rel = relb + fj * 16 + g4 * 4 + i;
                        rel = rel < -MAXD ? -MAXD : (rel > MAXD ? MAXD : rel);
                        sv[fj][i] = fmaf(sacc[qq][fj][i], C2, bias2s[rel + MAXD] + cm[fj][i]);
                    }
            }

            float mx = sv[0][0];
#pragma unroll
            for (int fj = 0; fj < 4; fj++)
#pragma unroll
                for (int i = 0; i < 4; i++) mx = fmaxf(mx, sv[fj][i]);
            mx = fmaxf(mx, __shfl_xor(mx, 16));
            mx = fmaxf(mx, __shfl_xor(mx, 32));
            if (!__all(mx - m_prev[qq] <= 8.f)) {
                const float mnew = fmaxf(m_prev[qq], mx);
                const float corr = fexp2(m_prev[qq] - mnew);
                l_sum[qq] *= corr;
                m_prev[qq] = mnew;
#pragma unroll
                for (int fd = 0; fd < 4; fd++) oacc[qq][fd] *= corr;
            }
            float rsum = 0.f;
            float pb[4][4];
#pragma unroll
            for (int fj = 0; fj < 4; fj++)
#pragma unroll
                for (int i = 0; i < 4; i++) {
                    float p = fexp2(sv[fj][i] - m_prev[qq]);
                    pb[fj][i] = p;
                    rsum += p;
                }
            rsum += __shfl_xor(rsum, 16);
            rsum += __shfl_xor(rsum, 32);
            l_sum[qq] += rsum;

#pragma unroll
            for (int fj = 0; fj < 4; fj++) {
                union { bf16 hh[4]; unsigned long long u; } pk;
                pk.hh[0] = (bf16)pb[fj][0]; pk.hh[1] = (bf16)pb[fj][1];
                pk.hh[2] = (bf16)pb[fj][2]; pk.hh[3] = (bf16)pb[fj][3];
                *(unsigned long long*)&Psh[w][qq][ln15 * PIT + fj * 16 + g4 * 4] = pk.u;
            }
        }

#pragma unroll
        for (int j = 0; j < 8; j++) {
            Vt[nxt3][(vd0 + j) * PIT + (vr ^ vsw)] = vA[j];
            Vt[nxt3][(vd0 + j) * PIT + ((vr + 32) ^ vsw)] = vB[j];
        }
        if (tid < 64) {
            int gk = k0 + 64 + tid;
            int pi = (gk <= 1024) ? gk - 1 : 0;
            colm[curM ^ 1][tid] = (gk > 1024 || pad[(size_t)b * S + pi]) ? -1e9f : 0.f;
        }

        LGKM_BARRIER();   // single barrier per tile

        bf16x8 pa[2][2];
#pragma unroll
        for (int qq = 0; qq < 2; qq++) {
            pa[qq][0] = *(const bf16x8*)&Psh[w][qq][ln15 * PIT + kb8];
            pa[qq][1] = *(const bf16x8*)&Psh[w][qq][ln15 * PIT + 32 + kb8];
        }
#pragma unroll
        for (int fd = 0; fd < 4; fd++) {
            const int d = fd * 16 + ln15;
            const int vx = ((d >> 3) & 7) << 3;
            bf16x8 af0 = *(const bf16x8*)&Vt[cur3][d * PIT + (kb8 ^ vx)];
            bf16x8 af1 = *(const bf16x8*)&Vt[cur3][d * PIT + ((32 + kb8) ^ vx)];
            oacc[0][fd] = __builtin_amdgcn_mfma_f32_16x16x32_bf16(af0, pa[0][0], oacc[0][fd], 0, 0, 0);
            oacc[0][fd] = __builtin_amdgcn_mfma_f32_16x16x32_bf16(af1, pa[0][1], oacc[0][fd], 0, 0, 0);
            oacc[1][fd] = __builtin_amdgcn_mfma_f32_16x16x32_bf16(af0, pa[1][0], oacc[1][fd], 0, 0, 0);
            oacc[1][fd] = __builtin_amdgcn_mfma_f32_16x16x32_bf16(af1, pa[1][1], oacc[1][fd], 0, 0, 0);
        }
        cur3 = nxt3;
    }

    // epilogue: normalized partial O + (m, l) per q-row
#pragma unroll
    for (int qq = 0; qq < 2; qq++) {
        if (qrow[qq] < L) {
            const float inv = 1.f / l_sum[qq];
            bf16* op = opart + (size_t)(b * L + qrow[qq]) * D + h * HD + g4 * 4;
#pragma unroll
            for (int fd = 0; fd < 4; fd++) {
                bf16x4 r;
#pragma unroll
                for (int i = 0; i < 4; i++) r[i] = (bf16)(oacc[qq][fd][i] * inv);
                *(bf16x4*)(op + fd * 16) = r;
            }
            if (g4 == 0)
                mlout[(size_t)(z * 64 + b * 8 + h) * 1025 + qrow[qq]] =
                    make_float2(m_prev[qq], l_sum[qq]);
        }
    }
}

// ---------------- out = LayerNorm(xin + rin), wave-per-row, no LDS -----------
__global__ __launch_bounds__(256) void add_ln_k(const bf16* __restrict__ xin,
                                                const bf16* __restrict__ rin,
                                                const float* __restrict__ g,
                                                const float* __restrict__ bb,
                                                bf16* __restrict__ outb)
{
    int row = blockIdx.x * 4 + (threadIdx.x >> 6);
    int lane = threadIdx.x & 63;
    bf16x8 a = reinterpret_cast<const bf16x8*>(xin + (size_t)row * D)[lane];
    bf16x8 r = reinterpret_cast<const bf16x8*>(rin + (size_t)row * D)[lane];
    float v[8];
    float s = 0.f;
#pragma unroll
    for (int j = 0; j < 8; j++) {
        v[j] = (float)a[j] + (float)r[j];
        s += v[j];
    }
#pragma unroll
    for (int off = 1; off < 64; off <<= 1) s += __shfl_xor(s, off, 64);
    float mean = s * (1.f / D);
    float sq = 0.f;
#pragma unroll
    for (int j = 0; j < 8; j++) {
        v[j] -= mean;
        sq += v[j] * v[j];
    }
#pragma unroll
    for (int off = 1; off < 64; off <<= 1) sq += __shfl_xor(sq, off, 64);
    float rs = rsqrtf(sq * (1.f / D) + 1e-5f);
    float4 g0 = reinterpret_cast<const float4*>(g)[lane * 2];
    float4 g1 = reinterpret_cast<const float4*>(g)[lane * 2 + 1];
    float4 b0 = reinterpret_cast<const float4*>(bb)[lane * 2];
    float4 b1 = reinterpret_cast<const float4*>(bb)[lane * 2 + 1];
    float gg[8] = {g0.x, g0.y, g0.z, g0.w, g1.x, g1.y, g1.z, g1.w};
    float bbv[8] = {b0.x, b0.y, b0.z, b0.w, b1.x, b1.y, b1.z, b1.w};
    bf16x8 o;
#pragma unroll
    for (int j = 0; j < 8; j++)
        o[j] = (bf16)(v[j] * rs * gg[j] + bbv[j]);
    reinterpret_cast<bf16x8*>(outb + (size_t)row * D)[lane] = o;
}

// ---------------- final LN (row 0 only, bf16 in) + classifier ----------------
__global__ __launch_bounds__(256) void cls_k(const bf16* __restrict__ x,
                                             const float* __restrict__ ng,
                                             const float* __restrict__ nb,
                                             const float* __restrict__ cw,
                                             const float* __restrict__ cb,
                                             float* __restrict__ out)
{
    int b = blockIdx.x;
    __shared__ float xn[D];
    __shared__ float red[8];
    int tid = threadIdx.x;
    const bf16* xp = x + (size_t)(b * L) * D;
    float v0 = (float)xp[tid], v1 = (float)xp[tid + 256];
    float s = v0 + v1;
    for (int off = 32; off; off >>= 1) s += __shfl_down(s, off, 64);
    int lane = tid & 63, wid = tid >> 6;
    if (lane == 0) red[wid] = s;
    __syncthreads();
    if (tid == 0) red[0] = red[0] + red[1] + red[2] + red[3];
    __syncthreads();
    float mean = red[0] * (1.f / D);
    float d0 = v0 - mean, d1 = v1 - mean;
    float sq = d0 * d0 + d1 * d1;
    for (int off = 32; off; off >>= 1) sq += __shfl_down(sq, off, 64);
    if (lane == 0) red[4 + wid] = sq;
    __syncthreads();
    if (tid == 0) red[4] = red[4] + red[5] + red[6] + red[7];
    __syncthreads();
    float rs = rsqrtf(red[4] * (1.f / D) + 1e-5f);
    xn[tid] = d0 * rs * ng[tid] + nb[tid];
    xn[tid + 256] = d1 * rs * ng[tid + 256] + nb[tid + 256];
    __syncthreads();
    for (int o = tid; o < OUTLEN * NC; o += 256) {
        float acc = cb[o];
        const float* wp = cw + (size_t)o * D;
        for (int d = 0; d < D; d++) acc += xn[d] * wp[d];
        out[b * OUTLEN * NC + o] = acc;
    }
}

extern "C" void kernel_launch(void* const* d_in, const int* in_sizes, int n_in,
                              void* d_out, int out_size, void* d_ws, size_t ws_size,
                              hipStream_t stream) {
    const int* src = (const int*)d_in[0];
    const unsigned char* pad = (const unsigned char*)d_in[1];
    const float* emb = (const float*)d_in[2];
    const float* cls_token = (const float*)d_in[3];
    const float* qkv_w = (const float*)d_in[4];
    const float* qkv_b = (const float*)d_in[5];
    const float* out_w = (const float*)d_in[6];
    const float* out_b = (const float*)d_in[7];
    const float* rel_emb = (const float*)d_in[8];
    const float* ln1_g = (const float*)d_in[9];
    const float* ln1_b = (const float*)d_in[10];
    const float* w1 = (const float*)d_in[11];
    const float* b1 = (const float*)d_in[12];
    const float* w2 = (const float*)d_in[13];
    const float* b2 = (const float*)d_in[14];
    const float* ln2_g = (const float*)d_in[15];
    const float* ln2_b = (const float*)d_in[16];
    const float* norm_g = (const float*)d_in[17];
    const float* norm_b = (const float*)d_in[18];
    const float* cls_w = (const float*)d_in[19];
    const float* cls_b = (const float*)d_in[20];
    float* out = (float*)d_out;

    char* ws = (char*)d_ws;
    size_t off = 0;
    bf16*  xb  = (bf16*) (ws + off); off += (size_t)MP * D * 2;
    bf16*  x2b = (bf16*) (ws + off); off += (size_t)MP * D * 2;
    char*  R   = ws + off;           off += (size_t)MP * 3 * D * 4;
    bf16*  qkvb = (bf16*)R;
    bf16*  hb  = (bf16*)R;
    bf16*  pb  = (bf16*)(R + (size_t)MP * FF * 2);
    float2* mlbuf = (float2*)(R + (size_t)MP * FF * 2 + (size_t)MP * D * 2);
    bf16*  obf = (bf16*) (ws + off); off += (size_t)MP * D * 2;

    const size_t WQ = (size_t)NL * 3 * D * D;
    const size_t WO = (size_t)NL * D * D;
    const size_t W1E = (size_t)NL * FF * D;
    const size_t W2E = (size_t)NL * D * FF;
    const size_t WALL = WQ + WO + W1E + W2E;
    bool all_w = (off + WALL * 2) <= ws_size;

    bf16 *wq_a = nullptr, *wo_a = nullptr, *w1_a = nullptr, *w2_a = nullptr, *wbuf = nullptr;
    if (all_w) {
        wq_a = (bf16*)(ws + off);
        wo_a = wq_a + WQ;
        w1_a = wo_a + WO;
        w2_a = w1_a + W1E;
        int n4;
        n4 = (int)(WQ / 4);  cvt_k<<<dim3((n4 + 255) / 256), 256, 0, stream>>>(qkv_w, wq_a, n4);
        n4 = (int)(WO / 4);  cvt_k<<<dim3((n4 + 255) / 256), 256, 0, stream>>>(out_w, wo_a, n4);
        n4 = (int)(W1E / 4); cvt_k<<<dim3((n4 + 255) / 256), 256, 0, stream>>>(w1, w1_a, n4);
        n4 = (int)(W2E / 4); cvt_k<<<dim3((n4 + 255) / 256), 256, 0, stream>>>(w2, w2_a, n4);
    } else {
        wbuf = (bf16*)(ws + off);
    }

    const int M = B * L;
    {
        long total = (long)B * L * D;
        embed_k<<<dim3((unsigned)((total + 255) / 256)), 256, 0, stream>>>(src, emb, cls_token, xb);
    }
    for (int l = 0; l < NL; l++) {
        const float* qb  = qkv_b + (size_t)l * 3 * D;
        const float* obi = out_b + (size_t)l * D;
        const float* re  = rel_emb + (size_t)l * (2 * MAXD + 1) * H;
        const float* g1  = ln1_g + (size_t)l * D;
        const float* be1 = ln1_b + (size_t)l * D;
        const float* B1p = b1 + (size_t)l * FF;
        const float* B2p = b2 + (size_t)l * D;
        const float* g2  = ln2_g + (size_t)l * D;
        const float* be2 = ln2_b + (size_t)l * D;

        const bf16 *wqb, *wob, *w1b, *w2b;
        if (all_w) {
            wqb = wq_a + (size_t)l * 3 * D * D;
            wob = wo_a + (size_t)l * D * D;
            w1b = w1_a + (size_t)l * FF * D;
            w2b = w2_a + (size_t)l * D * FF;
        } else {
            bf16* wp_ = wbuf;
            wqb = wp_;            wp_ += 3 * D * D;
            wob = wp_;            wp_ += D * D;
            w1b = wp_;            wp_ += FF * D;
            w2b = wp_;
            int n4;
            n4 = 3 * D * D / 4; cvt_k<<<dim3((n4 + 255) / 256), 256, 0, stream>>>(qkv_w + (size_t)l * 3 * D * D, (bf16*)wqb, n4);
            n4 = D * D / 4;     cvt_k<<<dim3((n4 + 255) / 256), 256, 0, stream>>>(out_w + (size_t)l * D * D, (bf16*)wob, n4);
            n4 = FF * D / 4;    cvt_k<<<dim3((n4 + 255) / 256), 256, 0, stream>>>(w1 + (size_t)l * FF * D, (bf16*)w1b, n4);
            n4 = D * FF / 4;    cvt_k<<<dim3((n4 + 255) / 256), 256, 0, stream>>>(w2 + (size_t)l * D * FF, (bf16*)w2b, n4);
        }

        mgemm<0, 1, 1, 128, 0><<<dim3(3 * D / 128, MP / 128), 256, 0, stream>>>(xb, nullptr, nullptr, wqb, qb, nullptr, qkvb, 3 * D, D, D);
        fattn_k<<<dim3(B * H, 9, 2), 256, 0, stream>>>(qkvb, re, pad, x2b, obf, mlbuf);
        // out-proj with fused combine: A = s1*x2b + s2*obf (flash-decode merge)
        mgemm<0, 1, 1, 64, 1><<<dim3(D / 128, MP / 64), 256, 0, stream>>>(x2b, obf, mlbuf, wob, obi, nullptr, pb, D, D, D);
        add_ln_k<<<dim3(M / 4), 256, 0, stream>>>(xb, pb, g1, be1, x2b);
        mgemm<1, 1, 1, 128, 0><<<dim3(FF / 128, MP / 128), 256, 0, stream>>>(x2b, nullptr, nullptr, w1b, B1p, nullptr, hb, FF, D, D);
        mgemm<0, 1, 1, 64, 0><<<dim3(D / 128, MP / 64), 256, 0, stream>>>(hb, nullptr, nullptr, w2b, B2p, nullptr, pb, D, FF, FF);
        add_ln_k<<<dim3(M / 4), 256, 0, stream>>>(x2b, pb, g2, be2, xb);
    }
    cls_k<<<dim3(B), 256, 0, stream>>>(xb, norm_g, norm_b, cls_w, cls_b, out);
}

// Round 25
// 1352.295 us; speedup vs baseline: 1.0301x; 1.0301x over previous
//
#include <hip/hip_runtime.h>
#include <hip/hip_bf16.h>
#include <stdint.h>

#define B 8
#define S 1024
#define L 1025
#define D 512
#define H 8
#define HD 64
#define NL 6
#define FF 2048
#define MAXD 64
#define OUTLEN 8
#define NC 10

#define MP 8320   // 65 * 128, padded M

typedef __bf16 bf16;
typedef __bf16 bf16x8 __attribute__((ext_vector_type(8)));
typedef __bf16 bf16x4 __attribute__((ext_vector_type(4)));
typedef __bf16 bf16x2 __attribute__((ext_vector_type(2)));
typedef float f32x4 __attribute__((ext_vector_type(4)));

__device__ __forceinline__ float fexp2(float x) { return __builtin_amdgcn_exp2f(x); }

// barrier WITHOUT the vmcnt(0) drain
#define LGKM_BARRIER() asm volatile("s_waitcnt lgkmcnt(0)\ns_barrier" ::: "memory")

__device__ __forceinline__ void gld16(const void* g, void* l) {
    __builtin_amdgcn_global_load_lds(
        (const __attribute__((address_space(1))) unsigned int*)g,
        (__attribute__((address_space(3))) unsigned int*)l,
        16, 0, 0);
}

// GELU with A&S 7.1.26 erf (|err| <= 1.5e-7), no libm call
__device__ __forceinline__ float fast_gelu(float v) {
    float x = v * 0.70710678118654752f;
    float ax = fabsf(x);
    float t = 1.f / fmaf(0.3275911f, ax, 1.f);
    float poly = t * (0.254829592f + t * (-0.284496736f + t * (1.421413741f +
                 t * (-1.453152027f + t * 1.061405429f))));
    float e = fexp2(-ax * ax * 1.4426950408889634f);
    float erfv = 1.f - poly * e;
    erfv = copysignf(erfv, x);
    return 0.5f * v * (1.f + erfv);
}

// ---------------- f32 -> bf16 conversion (vectorized) ----------------
__global__ __launch_bounds__(256) void cvt_k(const float* __restrict__ in,
                                             bf16* __restrict__ out, int n4)
{
    int i = blockIdx.x * 256 + threadIdx.x;
    if (i >= n4) return;
    float4 v = reinterpret_cast<const float4*>(in)[i];
    bf16x4 o;
    o[0] = (bf16)v.x; o[1] = (bf16)v.y; o[2] = (bf16)v.z; o[3] = (bf16)v.w;
    reinterpret_cast<bf16x4*>(out)[i] = o;
}

// ---------------- embedding (vectorized: 1 thread = 8 d-elems) ----------------
__global__ __launch_bounds__(256) void embed_k(const int* __restrict__ src,
                                               const float* __restrict__ emb,
                                               const float* __restrict__ cls,
                                               bf16* __restrict__ xb)
{
    int i8 = blockIdx.x * 256 + threadIdx.x;   // over B*L*D/8
    if (i8 >= B * L * D / 8) return;
    int d0 = (i8 & 63) * 8;
    int bl = i8 >> 6;
    int l = bl % L;
    int b = bl / L;
    const float* srcp = (l == 0) ? (cls + d0)
                                 : (emb + (size_t)src[b * S + (l - 1)] * D + d0);
    float4 v0 = reinterpret_cast<const float4*>(srcp)[0];
    float4 v1 = reinterpret_cast<const float4*>(srcp)[1];
    bf16x8 o;
    o[0] = (bf16)v0.x; o[1] = (bf16)v0.y; o[2] = (bf16)v0.z; o[3] = (bf16)v0.w;
    o[4] = (bf16)v1.x; o[5] = (bf16)v1.y; o[6] = (bf16)v1.z; o[7] = (bf16)v1.w;
    *reinterpret_cast<bf16x8*>(xb + (size_t)i8 * 8) = o;
}

// ---------------- MFMA bf16 GEMM, 2-phase double-buffered LDS (R19) ----------
template<int ACT, int OBF, int BIAS, int RT>
__global__ __launch_bounds__(256) void mgemm(const bf16* __restrict__ A,
                                             const bf16* __restrict__ W,
                                             const float* __restrict__ bias,
                                             float* __restrict__ Cf,
                                             bf16* __restrict__ Cb,
                                             int N, int K, int LDA)
{
    __shared__ bf16 Asl[2][RT * 32];
    __shared__ bf16 Bsl[2][128 * 32];
    int tid = threadIdx.x;
    int m0 = blockIdx.y * RT;
    int n0 = blockIdx.x * 128;
    int lane = tid & 63;
    int w = tid >> 6;
    int wbase = tid & ~63;
    int kb = (lane >> 4) * 8;
    int rsel = lane & 15;
    constexpr int FJ = (RT == 128) ? 4 : 2;
    constexpr int CW = (RT == 128) ? 64 : 32;
    int wr, wc;
    if constexpr (RT == 128) { wr = w >> 1; wc = w & 1; }
    else                     { wr = 0;      wc = w;     }
    f32x4 acc[4][FJ] = {};

    auto stage = [&](int buf, int k0) {
        if constexpr (RT == 128) {
#pragma unroll
            for (int r = 0; r < 2; r++) {
                int s = r * 256 + tid;
                int sb = r * 256 + wbase;
                gld16(A + (size_t)(m0 + (s >> 2)) * LDA + k0 + (s & 3) * 8, &Asl[buf][(size_t)sb * 8]);
                gld16(W + (size_t)(n0 + (s >> 2)) * LDA + k0 + (s & 3) * 8, &Bsl[buf][(size_t)sb * 8]);
            }
        } else {
            gld16(A + (size_t)(m0 + (tid >> 2)) * LDA + k0 + (tid & 3) * 8, &Asl[buf][(size_t)wbase * 8]);
#pragma unroll
            for (int r = 0; r < 2; r++) {
                int s = r * 256 + tid;
                int sb = r * 256 + wbase;
                gld16(W + (size_t)(n0 + (s >> 2)) * LDA + k0 + (s & 3) * 8, &Bsl[buf][(size_t)sb * 8]);
            }
        }
    };

    stage(0, 0);
    __syncthreads();

    for (int k0 = 0; k0 < K; k0 += 32) {
        int cur = (k0 >> 5) & 1;
        if (k0 + 32 < K) stage(cur ^ 1, k0 + 32);
        bf16x8 af[4], bfr[FJ];
#pragma unroll
        for (int fi = 0; fi < 4; fi++)
            af[fi] = *reinterpret_cast<const bf16x8*>(&Asl[cur][(wr * 64 + fi * 16 + rsel) * 32 + kb]);
#pragma unroll
        for (int fj = 0; fj < FJ; fj++)
            bfr[fj] = *reinterpret_cast<const bf16x8*>(&Bsl[cur][(wc * CW + fj * 16 + rsel) * 32 + kb]);
#pragma unroll
        for (int fi = 0; fi < 4; fi++)
#pragma unroll
            for (int fj = 0; fj < FJ; fj++)
                acc[fi][fj] = __builtin_amdgcn_mfma_f32_16x16x32_bf16(af[fi], bfr[fj], acc[fi][fj], 0, 0, 0);
        __syncthreads();
    }
    int rowb = (lane >> 4) * 4;
    int colb = lane & 15;
#pragma unroll
    for (int fi = 0; fi < 4; fi++) {
#pragma unroll
        for (int fj = 0; fj < FJ; fj++) {
            int col = n0 + wc * CW + fj * 16 + colb;
            float bsv = BIAS ? bias[col] : 0.f;
#pragma unroll
            for (int i = 0; i < 4; i++) {
                int row = m0 + wr * 64 + fi * 16 + rowb + i;
                float v = acc[fi][fj][i] + bsv;
                if (ACT) v = fast_gelu(v);
                if (OBF) Cb[(size_t)row * N + col] = (bf16)v;
                else     Cf[(size_t)row * N + col] = v;
            }
        }
    }
}

// ---------------- MFMA flash attention v10: KV-split + defer-max (T13) -------
__global__ __launch_bounds__(256) void fattn_k(const bf16* __restrict__ qkv,
                                               const float* __restrict__ rel_emb_l,
                                               const unsigned char* __restrict__ pad,
                                               bf16* __restrict__ op0,
                                               bf16* __restrict__ op1,
                                               float2* __restrict__ mlout)
{
    constexpr int PIT = 72;
    __shared__ bf16 Vt[3][64 * PIT];
    __shared__ bf16 Psh[4][2][16 * PIT];
    __shared__ float bias2s[2 * MAXD + 1];
    __shared__ float colm[2][64];

    const int bh = blockIdx.x;
    const int qt = blockIdx.y;
    const int z = blockIdx.z;
    const int tbeg = z ? 9 : 0;
    const int tend = z ? 17 : 9;
    bf16* opart = z ? op1 : op0;
    const int h = bh & 7, b = bh >> 3;
    const int q0 = qt * 128;
    const int tid = threadIdx.x;
    const int lane = tid & 63;
    const int w = tid >> 6;
    const int ln15 = lane & 15, g4 = lane >> 4;
    const int kb8 = g4 * 8;
    constexpr float LOG2E = 1.4426950408889634f;
    constexpr float C2 = 0.125f * LOG2E;

    const char* base = (const char*)qkv + (size_t)(b * L) * 3072 + (size_t)h * (HD * 2);

    for (int i = tid; i < 2 * MAXD + 1; i += 256) bias2s[i] = rel_emb_l[i * H + h] * LOG2E;
    if (tid < 64) {
        int gk0 = tbeg * 64 + tid;
        int pi = (gk0 > 0 && gk0 <= 1024) ? gk0 - 1 : 0;
        colm[tbeg & 1][tid] = (gk0 > 1024 || (gk0 > 0 && pad[(size_t)b * S + pi])) ? -1e9f : 0.f;
    }

    int qrow[2];
    bf16x8 qa[2][2];
#pragma unroll
    for (int qq = 0; qq < 2; qq++) {
        qrow[qq] = q0 + qq * 64 + w * 16 + ln15;
        qa[qq][0] = *(const bf16x8*)(base + (size_t)qrow[qq] * 3072 + g4 * 16);
        qa[qq][1] = *(const bf16x8*)(base + (size_t)qrow[qq] * 3072 + 64 + g4 * 16);
    }

    const int vr = tid >> 3;
    const int vd0 = (tid & 7) * 8;
    const int vsw = ((vd0 >> 3) & 7) << 3;

    { // prologue: stage V tile tbeg into Vt[0]
        int kv0 = tbeg * 64;
        bf16x8 a = *(const bf16x8*)(base + (size_t)(kv0 + vr) * 3072 + 2048 + vd0 * 2);
        bf16x8 c = *(const bf16x8*)(base + (size_t)(kv0 + vr + 32) * 3072 + 2048 + vd0 * 2);
#pragma unroll
        for (int j = 0; j < 8; j++) {
            Vt[0][(vd0 + j) * PIT + (vr ^ vsw)] = a[j];
            Vt[0][(vd0 + j) * PIT + ((vr + 32) ^ vsw)] = c[j];
        }
    }
    bf16x8 kr[4][2];
#pragma unroll
    for (int fj = 0; fj < 4; fj++) {
        const char* rp = base + (size_t)(tbeg * 64 + fj * 16 + ln15) * 3072 + 1024 + g4 * 16;
        kr[fj][0] = *(const bf16x8*)(rp);
        kr[fj][1] = *(const bf16x8*)(rp + 64);
    }
    LGKM_BARRIER();

    f32x4 oacc[2][4] = {};
    float m_prev[2] = {-1e30f, -1e30f};
    float l_sum[2] = {0.f, 0.f};

    int cur3 = 0;
    for (int t = tbeg; t < tend; t++) {
        const int k0 = t * 64;
        const int k0n = (k0 + 64 > 1024) ? 1024 : (k0 + 64);
        const int curM = t & 1;
        int nxt3 = cur3 + 1; if (nxt3 == 3) nxt3 = 0;

        bf16x8 vA = *(const bf16x8*)(base + (size_t)(k0n + vr) * 3072 + 2048 + vd0 * 2);
        bf16x8 vB = *(const bf16x8*)(base + (size_t)(k0n + vr + 32) * 3072 + 2048 + vd0 * 2);

        f32x4 sacc[2][4] = {};
#pragma unroll
        for (int qq = 0; qq < 2; qq++)
#pragma unroll
            for (int fj = 0; fj < 4; fj++) {
                sacc[qq][fj] = __builtin_amdgcn_mfma_f32_16x16x32_bf16(kr[fj][0], qa[qq][0], sacc[qq][fj], 0, 0, 0);
                sacc[qq][fj] = __builtin_amdgcn_mfma_f32_16x16x32_bf16(kr[fj][1], qa[qq][1], sacc[qq][fj], 0, 0, 0);
            }
#pragma unroll
        for (int fj = 0; fj < 4; fj++) {
            const char* rp = base + (size_t)(k0n + fj * 16 + ln15) * 3072 + 1024 + g4 * 16;
            kr[fj][0] = *(const bf16x8*)(rp);
            kr[fj][1] = *(const bf16x8*)(rp + 64);
        }

        f32x4 cm[4];
#pragma unroll
        for (int fj = 0; fj < 4; fj++)
            cm[fj] = *(const f32x4*)&colm[curM][fj * 16 + g4 * 4];

#pragma unroll
        for (int qq = 0; qq < 2; qq++) {
            float sv[4][4];
            const int relbw = k0 - q0 - qq * 64 - w * 16;
            if (relbw >= MAXD + 15 || relbw <= -MAXD - 63) {
                const float bu = bias2s[relbw > 0 ? 2 * MAXD : 0];
#pragma unroll
                for (int fj = 0; fj < 4; fj++)
#pragma unroll
                    for (int i = 0; i < 4; i++)
                        sv[fj][i] = fmaf(sacc[qq][fj][i], C2, bu + cm[fj][i]);
            } else {
                const int relb = k0 - qrow[qq];
#pragma unroll
                for (int fj = 0; fj < 4; fj++)
#pragma unroll
                    for (int i = 0; i < 4; i++) {
                        int rel = relb + fj * 16 + g4 * 4 + i;
                        rel = rel < -MAXD ? -MAXD : (rel > MAXD ? MAXD : rel);
                        sv[fj][i] = fmaf(sacc[qq][fj][i], C2, bias2s[rel + MAXD] + cm[fj][i]);
                    }
            }

            float mx = sv[0][0];
#pragma unroll
            for (int fj = 0; fj < 4; fj++)
#pragma unroll
                for (int i = 0; i < 4; i++) mx = fmaxf(mx, sv[fj][i]);
            mx = fmaxf(mx, __shfl_xor(mx, 16));
            mx = fmaxf(mx, __shfl_xor(mx, 32));
            if (!__all(mx - m_prev[qq] <= 8.f)) {
                const float mnew = fmaxf(m_prev[qq], mx);
                const float corr = fexp2(m_prev[qq] - mnew);
                l_sum[qq] *= corr;
                m_prev[qq] = mnew;
#pragma unroll
                for (int fd = 0; fd < 4; fd++) oacc[qq][fd] *= corr;
            }
            float rsum = 0.f;
            float pb[4][4];
#pragma unroll
            for (int fj = 0; fj < 4; fj++)
#pragma unroll
                for (int i = 0; i < 4; i++) {
                    float p = fexp2(sv[fj][i] - m_prev[qq]);
                    pb[fj][i] = p;
                    rsum += p;
                }
            rsum += __shfl_xor(rsum, 16);
            rsum += __shfl_xor(rsum, 32);
            l_sum[qq] += rsum;

#pragma unroll
            for (int fj = 0; fj < 4; fj++) {
                union { bf16 hh[4]; unsigned long long u; } pk;
                pk.hh[0] = (bf16)pb[fj][0]; pk.hh[1] = (bf16)pb[fj][1];
                pk.hh[2] = (bf16)pb[fj][2]; pk.hh[3] = (bf16)pb[fj][3];
                *(unsigned long long*)&Psh[w][qq][ln15 * PIT + fj * 16 + g4 * 4] = pk.u;
            }
        }

#pragma unroll
        for (int j = 0; j < 8; j++) {
            Vt[nxt3][(vd0 + j) * PIT + (vr ^ vsw)] = vA[j];
            Vt[nxt3][(vd0 + j) * PIT + ((vr + 32) ^ vsw)] = vB[j];
        }
        if (tid < 64) {
            int gk = k0 + 64 + tid;
            int pi = (gk <= 1024) ? gk - 1 : 0;
            colm[curM ^ 1][tid] = (gk > 1024 || pad[(size_t)b * S + pi]) ? -1e9f : 0.f;
        }

        LGKM_BARRIER();   // single barrier per tile

        bf16x8 pa[2][2];
#pragma unroll
        for (int qq = 0; qq < 2; qq++) {
            pa[qq][0] = *(const bf16x8*)&Psh[w][qq][ln15 * PIT + kb8];
            pa[qq][1] = *(const bf16x8*)&Psh[w][qq][ln15 * PIT + 32 + kb8];
        }
#pragma unroll
        for (int fd = 0; fd < 4; fd++) {
            const int d = fd * 16 + ln15;
            const int vx = ((d >> 3) & 7) << 3;
            bf16x8 af0 = *(const bf16x8*)&Vt[cur3][d * PIT + (kb8 ^ vx)];
            bf16x8 af1 = *(const bf16x8*)&Vt[cur3][d * PIT + ((32 + kb8) ^ vx)];
            oacc[0][fd] = __builtin_amdgcn_mfma_f32_16x16x32_bf16(af0, pa[0][0], oacc[0][fd], 0, 0, 0);
            oacc[0][fd] = __builtin_amdgcn_mfma_f32_16x16x32_bf16(af1, pa[0][1], oacc[0][fd], 0, 0, 0);
            oacc[1][fd] = __builtin_amdgcn_mfma_f32_16x16x32_bf16(af0, pa[1][0], oacc[1][fd], 0, 0, 0);
            oacc[1][fd] = __builtin_amdgcn_mfma_f32_16x16x32_bf16(af1, pa[1][1], oacc[1][fd], 0, 0, 0);
        }
        cur3 = nxt3;
    }

    // epilogue: normalized partial O + (m, l) per q-row
#pragma unroll
    for (int qq = 0; qq < 2; qq++) {
        if (qrow[qq] < L) {
            const float inv = 1.f / l_sum[qq];
            bf16* op = opart + (size_t)(b * L + qrow[qq]) * D + h * HD + g4 * 4;
#pragma unroll
            for (int fd = 0; fd < 4; fd++) {
                bf16x4 r;
#pragma unroll
                for (int i = 0; i < 4; i++) r[i] = (bf16)(oacc[qq][fd][i] * inv);
                *(bf16x4*)(op + fd * 16) = r;
            }
            if (g4 == 0)
                mlout[(size_t)(z * 64 + b * 8 + h) * 1025 + qrow[qq]] =
                    make_float2(m_prev[qq], l_sum[qq]);
        }
    }
}

// ---------------- combine partials (flat, bf16x8 vectorized) ----------------
__global__ __launch_bounds__(256) void comb_k(const bf16* __restrict__ op0,
                                              const bf16* __restrict__ op1,
                                              const float2* __restrict__ ml,
                                              bf16* __restrict__ ob)
{
    int i8 = blockIdx.x * 256 + threadIdx.x;     // over M*D/8
    if (i8 >= B * L * D / 8) return;
    size_t idx = (size_t)i8 * 8;
    int row = (int)(idx >> 9);                   // / D
    int d = (int)(idx & 511);
    int h = d >> 6;
    int b = row / L, q = row - b * L;
    float2 a = ml[(size_t)(b * 8 + h) * 1025 + q];
    float2 c = ml[(size_t)(64 + b * 8 + h) * 1025 + q];
    float m = fmaxf(a.x, c.x);
    float s1 = a.y * fexp2(a.x - m);
    float s2 = c.y * fexp2(c.x - m);
    float inv = 1.f / (s1 + s2);
    s1 *= inv; s2 *= inv;
    bf16x8 v0 = *(const bf16x8*)(op0 + idx);
    bf16x8 v1 = *(const bf16x8*)(op1 + idx);
    bf16x8 o;
#pragma unroll
    for (int j = 0; j < 8; j++)
        o[j] = (bf16)(s1 * (float)v0[j] + s2 * (float)v1[j]);
    *(bf16x8*)(ob + idx) = o;
}

// ---------------- out = LayerNorm(xin + rin), wave-per-row, no LDS -----------
__global__ __launch_bounds__(256) void add_ln_k(const bf16* __restrict__ xin,
                                                const bf16* __restrict__ rin,
                                                const float* __restrict__ g,
                                                const float* __restrict__ bb,
                                                bf16* __restrict__ outb)
{
    int row = blockIdx.x * 4 + (threadIdx.x >> 6);
    int lane = threadIdx.x & 63;
    bf16x8 a = reinterpret_cast<const bf16x8*>(xin + (size_t)row * D)[lane];
    bf16x8 r = reinterpret_cast<const bf16x8*>(rin + (size_t)row * D)[lane];
    float v[8];
    float s = 0.f;
#pragma unroll
    for (int j = 0; j < 8; j++) {
        v[j] = (float)a[j] + (float)r[j];
        s += v[j];
    }
#pragma unroll
    for (int off = 1; off < 64; off <<= 1) s += __shfl_xor(s, off, 64);
    float mean = s * (1.f / D);
    float sq = 0.f;
#pragma unroll
    for (int j = 0; j < 8; j++) {
        v[j] -= mean;
        sq += v[j] * v[j];
    }
#pragma unroll
    for (int off = 1; off < 64; off <<= 1) sq += __shfl_xor(sq, off, 64);
    float rs = rsqrtf(sq * (1.f / D) + 1e-5f);
    float4 g0 = reinterpret_cast<const float4*>(g)[lane * 2];
    float4 g1 = reinterpret_cast<const float4*>(g)[lane * 2 + 1];
    float4 b0 = reinterpret_cast<const float4*>(bb)[lane * 2];
    float4 b1 = reinterpret_cast<const float4*>(bb)[lane * 2 + 1];
    float gg[8] = {g0.x, g0.y, g0.z, g0.w, g1.x, g1.y, g1.z, g1.w};
    float bbv[8] = {b0.x, b0.y, b0.z, b0.w, b1.x, b1.y, b1.z, b1.w};
    bf16x8 o;
#pragma unroll
    for (int j = 0; j < 8; j++)
        o[j] = (bf16)(v[j] * rs * gg[j] + bbv[j]);
    reinterpret_cast<bf16x8*>(outb + (size_t)row * D)[lane] = o;
}

// ---------------- final LN (row 0 only, bf16 in) + classifier ----------------
__global__ __launch_bounds__(256) void cls_k(const bf16* __restrict__ x,
                                             const float* __restrict__ ng,
                                             const float* __restrict__ nb,
                                             const float* __restrict__ cw,
                                             const float* __restrict__ cb,
                                             float* __restrict__ out)
{
    int b = blockIdx.x;
    __shared__ float xn[D];
    __shared__ float red[8];
    int tid = threadIdx.x;
    const bf16* xp = x + (size_t)(b * L) * D;
    float v0 = (float)xp[tid], v1 = (float)xp[tid + 256];
    float s = v0 + v1;
    for (int off = 32; off; off >>= 1) s += __shfl_down(s, off, 64);
    int lane = tid & 63, wid = tid >> 6;
    if (lane == 0) red[wid] = s;
    __syncthreads();
    if (tid == 0) red[0] = red[0] + red[1] + red[2] + red[3];
    __syncthreads();
    float mean = red[0] * (1.f / D);
    float d0 = v0 - mean, d1 = v1 - mean;
    float sq = d0 * d0 + d1 * d1;
    for (int off = 32; off; off >>= 1) sq += __shfl_down(sq, off, 64);
    if (lane == 0) red[4 + wid] = sq;
    __syncthreads();
    if (tid == 0) red[4] = red[4] + red[5] + red[6] + red[7];
    __syncthreads();
    float rs = rsqrtf(red[4] * (1.f / D) + 1e-5f);
    xn[tid] = d0 * rs * ng[tid] + nb[tid];
    xn[tid + 256] = d1 * rs * ng[tid + 256] + nb[tid + 256];
    __syncthreads();
    for (int o = tid; o < OUTLEN * NC; o += 256) {
        float acc = cb[o];
        const float* wp = cw + (size_t)o * D;
        for (int d = 0; d < D; d++) acc += xn[d] * wp[d];
        out[b * OUTLEN * NC + o] = acc;
    }
}

extern "C" void kernel_launch(void* const* d_in, const int* in_sizes, int n_in,
                              void* d_out, int out_size, void* d_ws, size_t ws_size,
                              hipStream_t stream) {
    const int* src = (const int*)d_in[0];
    const unsigned char* pad = (const unsigned char*)d_in[1];
    const float* emb = (const float*)d_in[2];
    const float* cls_token = (const float*)d_in[3];
    const float* qkv_w = (const float*)d_in[4];
    const float* qkv_b = (const float*)d_in[5];
    const float* out_w = (const float*)d_in[6];
    const float* out_b = (const float*)d_in[7];
    const float* rel_emb = (const float*)d_in[8];
    const float* ln1_g = (const float*)d_in[9];
    const float* ln1_b = (const float*)d_in[10];
    const float* w1 = (const float*)d_in[11];
    const float* b1 = (const float*)d_in[12];
    const float* w2 = (const float*)d_in[13];
    const float* b2 = (const float*)d_in[14];
    const float* ln2_g = (const float*)d_in[15];
    const float* ln2_b = (const float*)d_in[16];
    const float* norm_g = (const float*)d_in[17];
    const float* norm_b = (const float*)d_in[18];
    const float* cls_w = (const float*)d_in[19];
    const float* cls_b = (const float*)d_in[20];
    float* out = (float*)d_out;

    char* ws = (char*)d_ws;
    size_t off = 0;
    bf16*  xb  = (bf16*) (ws + off); off += (size_t)MP * D * 2;
    bf16*  x2b = (bf16*) (ws + off); off += (size_t)MP * D * 2;
    char*  R   = ws + off;           off += (size_t)MP * 3 * D * 4;
    bf16*  qkvb = (bf16*)R;
    bf16*  hb  = (bf16*)R;
    bf16*  pb  = (bf16*)(R + (size_t)MP * FF * 2);
    float2* mlbuf = (float2*)(R + (size_t)MP * FF * 2 + (size_t)MP * D * 2);
    bf16*  obf = (bf16*) (ws + off); off += (size_t)MP * D * 2;

    const size_t WQ = (size_t)NL * 3 * D * D;
    const size_t WO = (size_t)NL * D * D;
    const size_t W1E = (size_t)NL * FF * D;
    const size_t W2E = (size_t)NL * D * FF;
    const size_t WALL = WQ + WO + W1E + W2E;
    bool all_w = (off + WALL * 2) <= ws_size;

    bf16 *wq_a = nullptr, *wo_a = nullptr, *w1_a = nullptr, *w2_a = nullptr, *wbuf = nullptr;
    if (all_w) {
        wq_a = (bf16*)(ws + off);
        wo_a = wq_a + WQ;
        w1_a = wo_a + WO;
        w2_a = w1_a + W1E;
        int n4;
        n4 = (int)(WQ / 4);  cvt_k<<<dim3((n4 + 255) / 256), 256, 0, stream>>>(qkv_w, wq_a, n4);
        n4 = (int)(WO / 4);  cvt_k<<<dim3((n4 + 255) / 256), 256, 0, stream>>>(out_w, wo_a, n4);
        n4 = (int)(W1E / 4); cvt_k<<<dim3((n4 + 255) / 256), 256, 0, stream>>>(w1, w1_a, n4);
        n4 = (int)(W2E / 4); cvt_k<<<dim3((n4 + 255) / 256), 256, 0, stream>>>(w2, w2_a, n4);
    } else {
        wbuf = (bf16*)(ws + off);
    }

    const int M = B * L;
    {
        int n8 = B * L * D / 8;
        embed_k<<<dim3((n8 + 255) / 256), 256, 0, stream>>>(src, emb, cls_token, xb);
    }
    for (int l = 0; l < NL; l++) {
        const float* qb  = qkv_b + (size_t)l * 3 * D;
        const float* obi = out_b + (size_t)l * D;
        const float* re  = rel_emb + (size_t)l * (2 * MAXD + 1) * H;
        const float* g1  = ln1_g + (size_t)l * D;
        const float* be1 = ln1_b + (size_t)l * D;
        const float* B1p = b1 + (size_t)l * FF;
        const float* B2p = b2 + (size_t)l * D;
        const float* g2  = ln2_g + (size_t)l * D;
        const float* be2 = ln2_b + (size_t)l * D;

        const bf16 *wqb, *wob, *w1b, *w2b;
        if (all_w) {
            wqb = wq_a + (size_t)l * 3 * D * D;
            wob = wo_a + (size_t)l * D * D;
            w1b = w1_a + (size_t)l * FF * D;
            w2b = w2_a + (size_t)l * D * FF;
        } else {
            bf16* wp_ = wbuf;
            wqb = wp_;            wp_ += 3 * D * D;
            wob = wp_;            wp_ += D * D;
            w1b = wp_;            wp_ += FF * D;
            w2b = wp_;
            int n4;
            n4 = 3 * D * D / 4; cvt_k<<<dim3((n4 + 255) / 256), 256, 0, stream>>>(qkv_w + (size_t)l * 3 * D * D, (bf16*)wqb, n4);
            n4 = D * D / 4;     cvt_k<<<dim3((n4 + 255) / 256), 256, 0, stream>>>(out_w + (size_t)l * D * D, (bf16*)wob, n4);
            n4 = FF * D / 4;    cvt_k<<<dim3((n4 + 255) / 256), 256, 0, stream>>>(w1 + (size_t)l * FF * D, (bf16*)w1b, n4);
            n4 = D * FF / 4;    cvt_k<<<dim3((n4 + 255) / 256), 256, 0, stream>>>(w2 + (size_t)l * D * FF, (bf16*)w2b, n4);
        }

        mgemm<0, 1, 1, 128><<<dim3(3 * D / 128, MP / 128), 256, 0, stream>>>(xb, wqb, qb, nullptr, qkvb, 3 * D, D, D);
        fattn_k<<<dim3(B * H, 9, 2), 256, 0, stream>>>(qkvb, re, pad, x2b, obf, mlbuf);
        comb_k<<<dim3((B * L * D / 8 + 255) / 256), 256, 0, stream>>>(x2b, obf, mlbuf, obf);
        mgemm<0, 1, 1, 64><<<dim3(D / 128, MP / 64), 256, 0, stream>>>(obf, wob, obi, nullptr, pb, D, D, D);
        add_ln_k<<<dim3(M / 4), 256, 0, stream>>>(xb, pb, g1, be1, x2b);
        mgemm<1, 1, 1, 128><<<dim3(FF / 128, MP / 128), 256, 0, stream>>>(x2b, w1b, B1p, nullptr, hb, FF, D, D);
        mgemm<0, 1, 1, 64><<<dim3(D / 128, MP / 64), 256, 0, stream>>>(hb, w2b, B2p, nullptr, pb, D, FF, FF);
        add_ln_k<<<dim3(M / 4), 256, 0, stream>>>(x2b, pb, g2, be2, xb);
    }
    cls_k<<<dim3(B), 256, 0, stream>>>(xb, norm_g, norm_b, cls_w, cls_b, out);
}

// Round 26
// 1345.602 us; speedup vs baseline: 1.0352x; 1.0050x over previous
//
#include <hip/hip_runtime.h>
#include <hip/hip_bf16.h>
#include <stdint.h>

#define B 8
#define S 1024
#define L 1025
#define D 512
#define H 8
#define HD 64
#define NL 6
#define FF 2048
#define MAXD 64
#define OUTLEN 8
#define NC 10

#define MP 8320   // 65 * 128, padded M

typedef __bf16 bf16;
typedef __bf16 bf16x8 __attribute__((ext_vector_type(8)));
typedef __bf16 bf16x4 __attribute__((ext_vector_type(4)));
typedef __bf16 bf16x2 __attribute__((ext_vector_type(2)));
typedef float f32x4 __attribute__((ext_vector_type(4)));

__device__ __forceinline__ float fexp2(float x) { return __builtin_amdgcn_exp2f(x); }

// barrier WITHOUT the vmcnt(0) drain
#define LGKM_BARRIER() asm volatile("s_waitcnt lgkmcnt(0)\ns_barrier" ::: "memory")

__device__ __forceinline__ void gld16(const void* g, void* l) {
    __builtin_amdgcn_global_load_lds(
        (const __attribute__((address_space(1))) unsigned int*)g,
        (__attribute__((address_space(3))) unsigned int*)l,
        16, 0, 0);
}

// GELU with A&S 7.1.26 erf (|err| <= 1.5e-7), no libm call
__device__ __forceinline__ float fast_gelu(float v) {
    float x = v * 0.70710678118654752f;
    float ax = fabsf(x);
    float t = 1.f / fmaf(0.3275911f, ax, 1.f);
    float poly = t * (0.254829592f + t * (-0.284496736f + t * (1.421413741f +
                 t * (-1.453152027f + t * 1.061405429f))));
    float e = fexp2(-ax * ax * 1.4426950408889634f);
    float erfv = 1.f - poly * e;
    erfv = copysignf(erfv, x);
    return 0.5f * v * (1.f + erfv);
}

// ---------------- f32 -> bf16 conversion (vectorized) ----------------
__global__ __launch_bounds__(256) void cvt_k(const float* __restrict__ in,
                                             bf16* __restrict__ out, int n4)
{
    int i = blockIdx.x * 256 + threadIdx.x;
    if (i >= n4) return;
    float4 v = reinterpret_cast<const float4*>(in)[i];
    bf16x4 o;
    o[0] = (bf16)v.x; o[1] = (bf16)v.y; o[2] = (bf16)v.z; o[3] = (bf16)v.w;
    reinterpret_cast<bf16x4*>(out)[i] = o;
}

// ---------------- embedding (vectorized: 1 thread = 8 d-elems) ----------------
__global__ __launch_bounds__(256) void embed_k(const int* __restrict__ src,
                                               const float* __restrict__ emb,
                                               const float* __restrict__ cls,
                                               bf16* __restrict__ xb)
{
    int i8 = blockIdx.x * 256 + threadIdx.x;   // over B*L*D/8
    if (i8 >= B * L * D / 8) return;
    int d0 = (i8 & 63) * 8;
    int bl = i8 >> 6;
    int l = bl % L;
    int b = bl / L;
    const float* srcp = (l == 0) ? (cls + d0)
                                 : (emb + (size_t)src[b * S + (l - 1)] * D + d0);
    float4 v0 = reinterpret_cast<const float4*>(srcp)[0];
    float4 v1 = reinterpret_cast<const float4*>(srcp)[1];
    bf16x8 o;
    o[0] = (bf16)v0.x; o[1] = (bf16)v0.y; o[2] = (bf16)v0.z; o[3] = (bf16)v0.w;
    o[4] = (bf16)v1.x; o[5] = (bf16)v1.y; o[6] = (bf16)v1.z; o[7] = (bf16)v1.w;
    *reinterpret_cast<bf16x8*>(xb + (size_t)i8 * 8) = o;
}

// ---------------- MFMA bf16 GEMM, 2-phase double-buffered LDS (R19) ----------
template<int ACT, int OBF, int BIAS, int RT>
__global__ __launch_bounds__(256) void mgemm(const bf16* __restrict__ A,
                                             const bf16* __restrict__ W,
                                             const float* __restrict__ bias,
                                             float* __restrict__ Cf,
                                             bf16* __restrict__ Cb,
                                             int N, int K, int LDA)
{
    __shared__ bf16 Asl[2][RT * 32];
    __shared__ bf16 Bsl[2][128 * 32];
    int tid = threadIdx.x;
    int m0 = blockIdx.y * RT;
    int n0 = blockIdx.x * 128;
    int lane = tid & 63;
    int w = tid >> 6;
    int wbase = tid & ~63;
    int kb = (lane >> 4) * 8;
    int rsel = lane & 15;
    constexpr int FJ = (RT == 128) ? 4 : 2;
    constexpr int CW = (RT == 128) ? 64 : 32;
    int wr, wc;
    if constexpr (RT == 128) { wr = w >> 1; wc = w & 1; }
    else                     { wr = 0;      wc = w;     }
    f32x4 acc[4][FJ] = {};

    auto stage = [&](int buf, int k0) {
        if constexpr (RT == 128) {
#pragma unroll
            for (int r = 0; r < 2; r++) {
                int s = r * 256 + tid;
                int sb = r * 256 + wbase;
                gld16(A + (size_t)(m0 + (s >> 2)) * LDA + k0 + (s & 3) * 8, &Asl[buf][(size_t)sb * 8]);
                gld16(W + (size_t)(n0 + (s >> 2)) * LDA + k0 + (s & 3) * 8, &Bsl[buf][(size_t)sb * 8]);
            }
        } else {
            gld16(A + (size_t)(m0 + (tid >> 2)) * LDA + k0 + (tid & 3) * 8, &Asl[buf][(size_t)wbase * 8]);
#pragma unroll
            for (int r = 0; r < 2; r++) {
                int s = r * 256 + tid;
                int sb = r * 256 + wbase;
                gld16(W + (size_t)(n0 + (s >> 2)) * LDA + k0 + (s & 3) * 8, &Bsl[buf][(size_t)sb * 8]);
            }
        }
    };

    stage(0, 0);
    __syncthreads();

    for (int k0 = 0; k0 < K; k0 += 32) {
        int cur = (k0 >> 5) & 1;
        if (k0 + 32 < K) stage(cur ^ 1, k0 + 32);
        bf16x8 af[4], bfr[FJ];
#pragma unroll
        for (int fi = 0; fi < 4; fi++)
            af[fi] = *reinterpret_cast<const bf16x8*>(&Asl[cur][(wr * 64 + fi * 16 + rsel) * 32 + kb]);
#pragma unroll
        for (int fj = 0; fj < FJ; fj++)
            bfr[fj] = *reinterpret_cast<const bf16x8*>(&Bsl[cur][(wc * CW + fj * 16 + rsel) * 32 + kb]);
#pragma unroll
        for (int fi = 0; fi < 4; fi++)
#pragma unroll
            for (int fj = 0; fj < FJ; fj++)
                acc[fi][fj] = __builtin_amdgcn_mfma_f32_16x16x32_bf16(af[fi], bfr[fj], acc[fi][fj], 0, 0, 0);
        __syncthreads();
    }
    int rowb = (lane >> 4) * 4;
    int colb = lane & 15;
#pragma unroll
    for (int fi = 0; fi < 4; fi++) {
#pragma unroll
        for (int fj = 0; fj < FJ; fj++) {
            int col = n0 + wc * CW + fj * 16 + colb;
            float bsv = BIAS ? bias[col] : 0.f;
#pragma unroll
            for (int i = 0; i < 4; i++) {
                int row = m0 + wr * 64 + fi * 16 + rowb + i;
                float v = acc[fi][fj][i] + bsv;
                if (ACT) v = fast_gelu(v);
                if (OBF) Cb[(size_t)row * N + col] = (bf16)v;
                else     Cf[(size_t)row * N + col] = v;
            }
        }
    }
}

// ---------------- MFMA flash attention v11: shared Psh + PV-before-barrier ----
// Psh is wave-private (same-wave lgkm ordering suffices); Vt[cur3] is visible
// from tile start (committed by previous tile's barrier). PV moves directly
// after each q-subtile's P-write; one Psh buffer shared across both subtiles.
// LDS 47.6 -> 37.9 KB => 4 blocks/CU (was 3).
__global__ __launch_bounds__(256) void fattn_k(const bf16* __restrict__ qkv,
                                               const float* __restrict__ rel_emb_l,
                                               const unsigned char* __restrict__ pad,
                                               bf16* __restrict__ op0,
                                               bf16* __restrict__ op1,
                                               float2* __restrict__ mlout)
{
    constexpr int PIT = 72;
    __shared__ bf16 Vt[3][64 * PIT];
    __shared__ bf16 Psh[4][16 * PIT];      // per-wave, shared across q-subtiles
    __shared__ float bias2s[2 * MAXD + 1];
    __shared__ float colm[2][64];

    const int bh = blockIdx.x;
    const int qt = blockIdx.y;
    const int z = blockIdx.z;
    const int tbeg = z ? 9 : 0;
    const int tend = z ? 17 : 9;
    bf16* opart = z ? op1 : op0;
    const int h = bh & 7, b = bh >> 3;
    const int q0 = qt * 128;
    const int tid = threadIdx.x;
    const int lane = tid & 63;
    const int w = tid >> 6;
    const int ln15 = lane & 15, g4 = lane >> 4;
    const int kb8 = g4 * 8;
    constexpr float LOG2E = 1.4426950408889634f;
    constexpr float C2 = 0.125f * LOG2E;

    const char* base = (const char*)qkv + (size_t)(b * L) * 3072 + (size_t)h * (HD * 2);

    for (int i = tid; i < 2 * MAXD + 1; i += 256) bias2s[i] = rel_emb_l[i * H + h] * LOG2E;
    if (tid < 64) {
        int gk0 = tbeg * 64 + tid;
        int pi = (gk0 > 0 && gk0 <= 1024) ? gk0 - 1 : 0;
        colm[tbeg & 1][tid] = (gk0 > 1024 || (gk0 > 0 && pad[(size_t)b * S + pi])) ? -1e9f : 0.f;
    }

    int qrow[2];
    bf16x8 qa[2][2];
#pragma unroll
    for (int qq = 0; qq < 2; qq++) {
        qrow[qq] = q0 + qq * 64 + w * 16 + ln15;
        qa[qq][0] = *(const bf16x8*)(base + (size_t)qrow[qq] * 3072 + g4 * 16);
        qa[qq][1] = *(const bf16x8*)(base + (size_t)qrow[qq] * 3072 + 64 + g4 * 16);
    }

    const int vr = tid >> 3;
    const int vd0 = (tid & 7) * 8;
    const int vsw = ((vd0 >> 3) & 7) << 3;

    { // prologue: stage V tile tbeg into Vt[0]
        int kv0 = tbeg * 64;
        bf16x8 a = *(const bf16x8*)(base + (size_t)(kv0 + vr) * 3072 + 2048 + vd0 * 2);
        bf16x8 c = *(const bf16x8*)(base + (size_t)(kv0 + vr + 32) * 3072 + 2048 + vd0 * 2);
#pragma unroll
        for (int j = 0; j < 8; j++) {
            Vt[0][(vd0 + j) * PIT + (vr ^ vsw)] = a[j];
            Vt[0][(vd0 + j) * PIT + ((vr + 32) ^ vsw)] = c[j];
        }
    }
    bf16x8 kr[4][2];
#pragma unroll
    for (int fj = 0; fj < 4; fj++) {
        const char* rp = base + (size_t)(tbeg * 64 + fj * 16 + ln15) * 3072 + 1024 + g4 * 16;
        kr[fj][0] = *(const bf16x8*)(rp);
        kr[fj][1] = *(const bf16x8*)(rp + 64);
    }
    LGKM_BARRIER();

    f32x4 oacc[2][4] = {};
    float m_prev[2] = {-1e30f, -1e30f};
    float l_sum[2] = {0.f, 0.f};

    int cur3 = 0;
    for (int t = tbeg; t < tend; t++) {
        const int k0 = t * 64;
        const int k0n = (k0 + 64 > 1024) ? 1024 : (k0 + 64);
        const int curM = t & 1;
        int nxt3 = cur3 + 1; if (nxt3 == 3) nxt3 = 0;

        bf16x8 vA = *(const bf16x8*)(base + (size_t)(k0n + vr) * 3072 + 2048 + vd0 * 2);
        bf16x8 vB = *(const bf16x8*)(base + (size_t)(k0n + vr + 32) * 3072 + 2048 + vd0 * 2);

        f32x4 sacc[2][4] = {};
#pragma unroll
        for (int qq = 0; qq < 2; qq++)
#pragma unroll
            for (int fj = 0; fj < 4; fj++) {
                sacc[qq][fj] = __builtin_amdgcn_mfma_f32_16x16x32_bf16(kr[fj][0], qa[qq][0], sacc[qq][fj], 0, 0, 0);
                sacc[qq][fj] = __builtin_amdgcn_mfma_f32_16x16x32_bf16(kr[fj][1], qa[qq][1], sacc[qq][fj], 0, 0, 0);
            }
#pragma unroll
        for (int fj = 0; fj < 4; fj++) {
            const char* rp = base + (size_t)(k0n + fj * 16 + ln15) * 3072 + 1024 + g4 * 16;
            kr[fj][0] = *(const bf16x8*)(rp);
            kr[fj][1] = *(const bf16x8*)(rp + 64);
        }

        f32x4 cm[4];
#pragma unroll
        for (int fj = 0; fj < 4; fj++)
            cm[fj] = *(const f32x4*)&colm[curM][fj * 16 + g4 * 4];

        // per-subtile: bias/mask + softmax + P-write + PV (Vt[cur3] visible
        // since the previous tile's barrier; Psh wave-private => no barrier)
#pragma unroll
        for (int qq = 0; qq < 2; qq++) {
            float sv[4][4];
            const int relbw = k0 - q0 - qq * 64 - w * 16;
            if (relbw >= MAXD + 15 || relbw <= -MAXD - 63) {
                const float bu = bias2s[relbw > 0 ? 2 * MAXD : 0];
#pragma unroll
                for (int fj = 0; fj < 4; fj++)
#pragma unroll
                    for (int i = 0; i < 4; i++)
                        sv[fj][i] = fmaf(sacc[qq][fj][i], C2, bu + cm[fj][i]);
            } else {
                const int relb = k0 - qrow[qq];
#pragma unroll
                for (int fj = 0; fj < 4; fj++)
#pragma unroll
                    for (int i = 0; i < 4; i++) {
                        int rel = relb + fj * 16 + g4 * 4 + i;
                        rel = rel < -MAXD ? -MAXD : (rel > MAXD ? MAXD : rel);
                        sv[fj][i] = fmaf(sacc[qq][fj][i], C2, bias2s[rel + MAXD] + cm[fj][i]);
                    }
            }

            float mx = sv[0][0];
#pragma unroll
            for (int fj = 0; fj < 4; fj++)
#pragma unroll
                for (int i = 0; i < 4; i++) mx = fmaxf(mx, sv[fj][i]);
            mx = fmaxf(mx, __shfl_xor(mx, 16));
            mx = fmaxf(mx, __shfl_xor(mx, 32));
            if (!__all(mx - m_prev[qq] <= 8.f)) {
                const float mnew = fmaxf(m_prev[qq], mx);
                const float corr = fexp2(m_prev[qq] - mnew);
                l_sum[qq] *= corr;
                m_prev[qq] = mnew;
#pragma unroll
                for (int fd = 0; fd < 4; fd++) oacc[qq][fd] *= corr;
            }
            float rsum = 0.f;
            float pb[4][4];
#pragma unroll
            for (int fj = 0; fj < 4; fj++)
#pragma unroll
                for (int i = 0; i < 4; i++) {
                    float p = fexp2(sv[fj][i] - m_prev[qq]);
                    pb[fj][i] = p;
                    rsum += p;
                }
            rsum += __shfl_xor(rsum, 16);
            rsum += __shfl_xor(rsum, 32);
            l_sum[qq] += rsum;

#pragma unroll
            for (int fj = 0; fj < 4; fj++) {
                union { bf16 hh[4]; unsigned long long u; } pk;
                pk.hh[0] = (bf16)pb[fj][0]; pk.hh[1] = (bf16)pb[fj][1];
                pk.hh[2] = (bf16)pb[fj][2]; pk.hh[3] = (bf16)pb[fj][3];
                *(unsigned long long*)&Psh[w][ln15 * PIT + fj * 16 + g4 * 4] = pk.u;
            }

            // PV for this subtile (same-wave lgkm ordering covers Psh RAW)
            bf16x8 pa0 = *(const bf16x8*)&Psh[w][ln15 * PIT + kb8];
            bf16x8 pa1 = *(const bf16x8*)&Psh[w][ln15 * PIT + 32 + kb8];
#pragma unroll
            for (int fd = 0; fd < 4; fd++) {
                const int d = fd * 16 + ln15;
                const int vx = ((d >> 3) & 7) << 3;
                bf16x8 af0 = *(const bf16x8*)&Vt[cur3][d * PIT + (kb8 ^ vx)];
                bf16x8 af1 = *(const bf16x8*)&Vt[cur3][d * PIT + ((32 + kb8) ^ vx)];
                oacc[qq][fd] = __builtin_amdgcn_mfma_f32_16x16x32_bf16(af0, pa0, oacc[qq][fd], 0, 0, 0);
                oacc[qq][fd] = __builtin_amdgcn_mfma_f32_16x16x32_bf16(af1, pa1, oacc[qq][fd], 0, 0, 0);
            }
        }

        // commit next V tile + next colm, then the single barrier
#pragma unroll
        for (int j = 0; j < 8; j++) {
            Vt[nxt3][(vd0 + j) * PIT + (vr ^ vsw)] = vA[j];
            Vt[nxt3][(vd0 + j) * PIT + ((vr + 32) ^ vsw)] = vB[j];
        }
        if (tid < 64) {
            int gk = k0 + 64 + tid;
            int pi = (gk <= 1024) ? gk - 1 : 0;
            colm[curM ^ 1][tid] = (gk > 1024 || pad[(size_t)b * S + pi]) ? -1e9f : 0.f;
        }

        LGKM_BARRIER();   // commits Vt[nxt3] + colm for tile t+1
        cur3 = nxt3;
    }

    // epilogue: normalized partial O + (m, l) per q-row
#pragma unroll
    for (int qq = 0; qq < 2; qq++) {
        if (qrow[qq] < L) {
            const float inv = 1.f / l_sum[qq];
            bf16* op = opart + (size_t)(b * L + qrow[qq]) * D + h * HD + g4 * 4;
#pragma unroll
            for (int fd = 0; fd < 4; fd++) {
                bf16x4 r;
#pragma unroll
                for (int i = 0; i < 4; i++) r[i] = (bf16)(oacc[qq][fd][i] * inv);
                *(bf16x4*)(op + fd * 16) = r;
            }
            if (g4 == 0)
                mlout[(size_t)(z * 64 + b * 8 + h) * 1025 + qrow[qq]] =
                    make_float2(m_prev[qq], l_sum[qq]);
        }
    }
}

// ---------------- combine partials (flat, bf16x8 vectorized) ----------------
__global__ __launch_bounds__(256) void comb_k(const bf16* __restrict__ op0,
                                              const bf16* __restrict__ op1,
                                              const float2* __restrict__ ml,
                                              bf16* __restrict__ ob)
{
    int i8 = blockIdx.x * 256 + threadIdx.x;     // over M*D/8
    if (i8 >= B * L * D / 8) return;
    size_t idx = (size_t)i8 * 8;
    int row = (int)(idx >> 9);                   // / D
    int d = (int)(idx & 511);
    int h = d >> 6;
    int b = row / L, q = row - b * L;
    float2 a = ml[(size_t)(b * 8 + h) * 1025 + q];
    float2 c = ml[(size_t)(64 + b * 8 + h) * 1025 + q];
    float m = fmaxf(a.x, c.x);
    float s1 = a.y * fexp2(a.x - m);
    float s2 = c.y * fexp2(c.x - m);
    float inv = 1.f / (s1 + s2);
    s1 *= inv; s2 *= inv;
    bf16x8 v0 = *(const bf16x8*)(op0 + idx);
    bf16x8 v1 = *(const bf16x8*)(op1 + idx);
    bf16x8 o;
#pragma unroll
    for (int j = 0; j < 8; j++)
        o[j] = (bf16)(s1 * (float)v0[j] + s2 * (float)v1[j]);
    *(bf16x8*)(ob + idx) = o;
}

// ---------------- out = LayerNorm(xin + rin), wave-per-row, no LDS -----------
__global__ __launch_bounds__(256) void add_ln_k(const bf16* __restrict__ xin,
                                                const bf16* __restrict__ rin,
                                                const float* __restrict__ g,
                                                const float* __restrict__ bb,
                                                bf16* __restrict__ outb)
{
    int row = blockIdx.x * 4 + (threadIdx.x >> 6);
    int lane = threadIdx.x & 63;
    bf16x8 a = reinterpret_cast<const bf16x8*>(xin + (size_t)row * D)[lane];
    bf16x8 r = reinterpret_cast<const bf16x8*>(rin + (size_t)row * D)[lane];
    float v[8];
    float s = 0.f;
#pragma unroll
    for (int j = 0; j < 8; j++) {
        v[j] = (float)a[j] + (float)r[j];
        s += v[j];
    }
#pragma unroll
    for (int off = 1; off < 64; off <<= 1) s += __shfl_xor(s, off, 64);
    float mean = s * (1.f / D);
    float sq = 0.f;
#pragma unroll
    for (int j = 0; j < 8; j++) {
        v[j] -= mean;
        sq += v[j] * v[j];
    }
#pragma unroll
    for (int off = 1; off < 64; off <<= 1) sq += __shfl_xor(sq, off, 64);
    float rs = rsqrtf(sq * (1.f / D) + 1e-5f);
    float4 g0 = reinterpret_cast<const float4*>(g)[lane * 2];
    float4 g1 = reinterpret_cast<const float4*>(g)[lane * 2 + 1];
    float4 b0 = reinterpret_cast<const float4*>(bb)[lane * 2];
    float4 b1 = reinterpret_cast<const float4*>(bb)[lane * 2 + 1];
    float gg[8] = {g0.x, g0.y, g0.z, g0.w, g1.x, g1.y, g1.z, g1.w};
    float bbv[8] = {b0.x, b0.y, b0.z, b0.w, b1.x, b1.y, b1.z, b1.w};
    bf16x8 o;
#pragma unroll
    for (int j = 0; j < 8; j++)
        o[j] = (bf16)(v[j] * rs * gg[j] + bbv[j]);
    reinterpret_cast<bf16x8*>(outb + (size_t)row * D)[lane] = o;
}

// ---------------- final LN (row 0 only, bf16 in) + classifier ----------------
__global__ __launch_bounds__(256) void cls_k(const bf16* __restrict__ x,
                                             const float* __restrict__ ng,
                                             const float* __restrict__ nb,
                                             const float* __restrict__ cw,
                                             const float* __restrict__ cb,
                                             float* __restrict__ out)
{
    int b = blockIdx.x;
    __shared__ float xn[D];
    __shared__ float red[8];
    int tid = threadIdx.x;
    const bf16* xp = x + (size_t)(b * L) * D;
    float v0 = (float)xp[tid], v1 = (float)xp[tid + 256];
    float s = v0 + v1;
    for (int off = 32; off; off >>= 1) s += __shfl_down(s, off, 64);
    int lane = tid & 63, wid = tid >> 6;
    if (lane == 0) red[wid] = s;
    __syncthreads();
    if (tid == 0) red[0] = red[0] + red[1] + red[2] + red[3];
    __syncthreads();
    float mean = red[0] * (1.f / D);
    float d0 = v0 - mean, d1 = v1 - mean;
    float sq = d0 * d0 + d1 * d1;
    for (int off = 32; off; off >>= 1) sq += __shfl_down(sq, off, 64);
    if (lane == 0) red[4 + wid] = sq;
    __syncthreads();
    if (tid == 0) red[4] = red[4] + red[5] + red[6] + red[7];
    __syncthreads();
    float rs = rsqrtf(red[4] * (1.f / D) + 1e-5f);
    xn[tid] = d0 * rs * ng[tid] + nb[tid];
    xn[tid + 256] = d1 * rs * ng[tid + 256] + nb[tid + 256];
    __syncthreads();
    for (int o = tid; o < OUTLEN * NC; o += 256) {
        float acc = cb[o];
        const float* wp = cw + (size_t)o * D;
        for (int d = 0; d < D; d++) acc += xn[d] * wp[d];
        out[b * OUTLEN * NC + o] = acc;
    }
}

extern "C" void kernel_launch(void* const* d_in, const int* in_sizes, int n_in,
                              void* d_out, int out_size, void* d_ws, size_t ws_size,
                              hipStream_t stream) {
    const int* src = (const int*)d_in[0];
    const unsigned char* pad = (const unsigned char*)d_in[1];
    const float* emb = (const float*)d_in[2];
    const float* cls_token = (const float*)d_in[3];
    const float* qkv_w = (const float*)d_in[4];
    const float* qkv_b = (const float*)d_in[5];
    const float* out_w = (const float*)d_in[6];
    const float* out_b = (const float*)d_in[7];
    const float* rel_emb = (const float*)d_in[8];
    const float* ln1_g = (const float*)d_in[9];
    const float* ln1_b = (const float*)d_in[10];
    const float* w1 = (const float*)d_in[11];
    const float* b1 = (const float*)d_in[12];
    const float* w2 = (const float*)d_in[13];
    const float* b2 = (const float*)d_in[14];
    const float* ln2_g = (const float*)d_in[15];
    const float* ln2_b = (const float*)d_in[16];
    const float* norm_g = (const float*)d_in[17];
    const float* norm_b = (const float*)d_in[18];
    const float* cls_w = (const float*)d_in[19];
    const float* cls_b = (const float*)d_in[20];
    float* out = (float*)d_out;

    char* ws = (char*)d_ws;
    size_t off = 0;
    bf16*  xb  = (bf16*) (ws + off); off += (size_t)MP * D * 2;
    bf16*  x2b = (bf16*) (ws + off); off += (size_t)MP * D * 2;
    char*  R   = ws + off;           off += (size_t)MP * 3 * D * 4;
    bf16*  qkvb = (bf16*)R;
    bf16*  hb  = (bf16*)R;
    bf16*  pb  = (bf16*)(R + (size_t)MP * FF * 2);
    float2* mlbuf = (float2*)(R + (size_t)MP * FF * 2 + (size_t)MP * D * 2);
    bf16*  obf = (bf16*) (ws + off); off += (size_t)MP * D * 2;

    const size_t WQ = (size_t)NL * 3 * D * D;
    const size_t WO = (size_t)NL * D * D;
    const size_t W1E = (size_t)NL * FF * D;
    const size_t W2E = (size_t)NL * D * FF;
    const size_t WALL = WQ + WO + W1E + W2E;
    bool all_w = (off + WALL * 2) <= ws_size;

    bf16 *wq_a = nullptr, *wo_a = nullptr, *w1_a = nullptr, *w2_a = nullptr, *wbuf = nullptr;
    if (all_w) {
        wq_a = (bf16*)(ws + off);
        wo_a = wq_a + WQ;
        w1_a = wo_a + WO;
        w2_a = w1_a + W1E;
        int n4;
        n4 = (int)(WQ / 4);  cvt_k<<<dim3((n4 + 255) / 256), 256, 0, stream>>>(qkv_w, wq_a, n4);
        n4 = (int)(WO / 4);  cvt_k<<<dim3((n4 + 255) / 256), 256, 0, stream>>>(out_w, wo_a, n4);
        n4 = (int)(W1E / 4); cvt_k<<<dim3((n4 + 255) / 256), 256, 0, stream>>>(w1, w1_a, n4);
        n4 = (int)(W2E / 4); cvt_k<<<dim3((n4 + 255) / 256), 256, 0, stream>>>(w2, w2_a, n4);
    } else {
        wbuf = (bf16*)(ws + off);
    }

    const int M = B * L;
    {
        int n8 = B * L * D / 8;
        embed_k<<<dim3((n8 + 255) / 256), 256, 0, stream>>>(src, emb, cls_token, xb);
    }
    for (int l = 0; l < NL; l++) {
        const float* qb  = qkv_b + (size_t)l * 3 * D;
        const float* obi = out_b + (size_t)l * D;
        const float* re  = rel_emb + (size_t)l * (2 * MAXD + 1) * H;
        const float* g1  = ln1_g + (size_t)l * D;
        const float* be1 = ln1_b + (size_t)l * D;
        const float* B1p = b1 + (size_t)l * FF;
        const float* B2p = b2 + (size_t)l * D;
        const float* g2  = ln2_g + (size_t)l * D;
        const float* be2 = ln2_b + (size_t)l * D;

        const bf16 *wqb, *wob, *w1b, *w2b;
        if (all_w) {
            wqb = wq_a + (size_t)l * 3 * D * D;
            wob = wo_a + (size_t)l * D * D;
            w1b = w1_a + (size_t)l * FF * D;
            w2b = w2_a + (size_t)l * D * FF;
        } else {
            bf16* wp_ = wbuf;
            wqb = wp_;            wp_ += 3 * D * D;
            wob = wp_;            wp_ += D * D;
            w1b = wp_;            wp_ += FF * D;
            w2b = wp_;
            int n4;
            n4 = 3 * D * D / 4; cvt_k<<<dim3((n4 + 255) / 256), 256, 0, stream>>>(qkv_w + (size_t)l * 3 * D * D, (bf16*)wqb, n4);
            n4 = D * D / 4;     cvt_k<<<dim3((n4 + 255) / 256), 256, 0, stream>>>(out_w + (size_t)l * D * D, (bf16*)wob, n4);
            n4 = FF * D / 4;    cvt_k<<<dim3((n4 + 255) / 256), 256, 0, stream>>>(w1 + (size_t)l * FF * D, (bf16*)w1b, n4);
            n4 = D * FF / 4;    cvt_k<<<dim3((n4 + 255) / 256), 256, 0, stream>>>(w2 + (size_t)l * D * FF, (bf16*)w2b, n4);
        }

        mgemm<0, 1, 1, 128><<<dim3(3 * D / 128, MP / 128), 256, 0, stream>>>(xb, wqb, qb, nullptr, qkvb, 3 * D, D, D);
        fattn_k<<<dim3(B * H, 9, 2), 256, 0, stream>>>(qkvb, re, pad, x2b, obf, mlbuf);
        comb_k<<<dim3((B * L * D / 8 + 255) / 256), 256, 0, stream>>>(x2b, obf, mlbuf, obf);
        mgemm<0, 1, 1, 64><<<dim3(D / 128, MP / 64), 256, 0, stream>>>(obf, wob, obi, nullptr, pb, D, D, D);
        add_ln_k<<<dim3(M / 4), 256, 0, stream>>>(xb, pb, g1, be1, x2b);
        mgemm<1, 1, 1, 128><<<dim3(FF / 128, MP / 128), 256, 0, stream>>>(x2b, w1b, B1p, nullptr, hb, FF, D, D);
        mgemm<0, 1, 1, 64><<<dim3(D / 128, MP / 64), 256, 0, stream>>>(hb, w2b, B2p, nullptr, pb, D, FF, FF);
        add_ln_k<<<dim3(M / 4), 256, 0, stream>>>(x2b, pb, g2, be2, xb);
    }
    cls_k<<<dim3(B), 256, 0, stream>>>(xb, norm_g, norm_b, cls_w, cls_b, out);
}